// Round 1
// baseline (102.471 us; speedup 1.0000x reference)
//
#include <hip/hip_runtime.h>
#include <math.h>

#define NUM_EXPERTS 16
#define HIDDEN 1024
#define INTER 768
#define TOKENS 64
#define TOPK 2
#define NPAIRS (TOKENS*TOPK)   // 128
#define GRP 8

// ---------------------------------------------------------------------------
// Pass 1: for each pair p routed to expert e:
//   h[p][o] = silu(x[t]·w1[e,o,:]) * (x[t]·w3[e,o,:]),  o in [0,768)
// grid = (24 row-chunks of 32, 16 experts), block = 256 (4 waves)
// ---------------------------------------------------------------------------
__global__ __launch_bounds__(256) void moe_pass1(
    const float* __restrict__ x,        // [64][1024]
    const int*   __restrict__ topk_ids, // [128]
    const float* __restrict__ w13,      // [16][1536][1024]
    float*       __restrict__ h)        // [128][768]
{
    const int e    = blockIdx.y;
    const int o0   = blockIdx.x * 32 + (threadIdx.x >> 6) * 8;
    const int tid  = threadIdx.x;
    const int lane = tid & 63;

    __shared__ int   s_plist[NPAIRS];
    __shared__ int   s_np;
    __shared__ float s_x[GRP][HIDDEN];   // 32 KB

    if (tid == 0) s_np = 0;
    __syncthreads();
    if (tid < NPAIRS) {
        if (topk_ids[tid] == e) {
            int idx = atomicAdd(&s_np, 1);
            s_plist[idx] = tid;
        }
    }
    __syncthreads();
    const int np = s_np;
    if (np == 0) return;

    const int ngroups = (np + GRP - 1) / GRP;

    for (int g = 0; g < ngroups; ++g) {
        const int gnp = min(GRP, np - g * GRP);
        // stage x vectors for this token group (coalesced float4)
        for (int idx = tid; idx < gnp * (HIDDEN/4); idx += 256) {
            int tau = idx / (HIDDEN/4);
            int c   = idx % (HIDDEN/4);
            int t   = s_plist[g*GRP + tau] >> 1;
            *(float4*)(&s_x[tau][c*4]) = *(const float4*)(x + (size_t)t*HIDDEN + c*4);
        }
        __syncthreads();

        #pragma unroll
        for (int r = 0; r < 8; ++r) {
            const int o = o0 + r;
            const float* w1row = w13 + ((size_t)e * (2*INTER) + o) * HIDDEN;
            const float* w3row = w13 + ((size_t)e * (2*INTER) + INTER + o) * HIDDEN;
            float4 a1[4], a3[4];
            #pragma unroll
            for (int j = 0; j < 4; ++j) {
                a1[j] = *(const float4*)(w1row + lane*4 + 256*j);
                a3[j] = *(const float4*)(w3row + lane*4 + 256*j);
            }
            for (int tau = 0; tau < gnp; ++tau) {
                float acc1 = 0.f, acc3 = 0.f;
                #pragma unroll
                for (int j = 0; j < 4; ++j) {
                    const float4 xv = *(const float4*)(&s_x[tau][lane*4 + 256*j]);
                    acc1 += a1[j].x*xv.x + a1[j].y*xv.y + a1[j].z*xv.z + a1[j].w*xv.w;
                    acc3 += a3[j].x*xv.x + a3[j].y*xv.y + a3[j].z*xv.z + a3[j].w*xv.w;
                }
                #pragma unroll
                for (int m = 32; m > 0; m >>= 1) {
                    acc1 += __shfl_xor(acc1, m, 64);
                    acc3 += __shfl_xor(acc3, m, 64);
                }
                if (lane == 0) {
                    int p = s_plist[g*GRP + tau];
                    float gate = acc1 / (1.f + expf(-acc1));
                    h[(size_t)p * INTER + o] = gate * acc3;
                }
            }
        }
        __syncthreads();
    }
}

// ---------------------------------------------------------------------------
// Pass 2: y[p][i] = sum_o h[p][o] * w2[e][i][o]
// grid = (32 row-chunks of 32, 16 experts), block = 256
// ---------------------------------------------------------------------------
__global__ __launch_bounds__(256) void moe_pass2(
    const int*   __restrict__ topk_ids, // [128]
    const float* __restrict__ w2,       // [16][1024][768]
    const float* __restrict__ h,        // [128][768]
    float*       __restrict__ y)        // [128][1024]
{
    const int e    = blockIdx.y;
    const int i0   = blockIdx.x * 32 + (threadIdx.x >> 6) * 8;
    const int tid  = threadIdx.x;
    const int lane = tid & 63;

    __shared__ int   s_plist[NPAIRS];
    __shared__ int   s_np;
    __shared__ float s_h[GRP][INTER];    // 24 KB

    if (tid == 0) s_np = 0;
    __syncthreads();
    if (tid < NPAIRS) {
        if (topk_ids[tid] == e) {
            int idx = atomicAdd(&s_np, 1);
            s_plist[idx] = tid;
        }
    }
    __syncthreads();
    const int np = s_np;
    if (np == 0) return;

    const int ngroups = (np + GRP - 1) / GRP;

    for (int g = 0; g < ngroups; ++g) {
        const int gnp = min(GRP, np - g * GRP);
        // stage h rows for this group
        for (int idx = tid; idx < gnp * (INTER/4); idx += 256) {
            int tau = idx / (INTER/4);
            int c   = idx % (INTER/4);
            int p   = s_plist[g*GRP + tau];
            *(float4*)(&s_h[tau][c*4]) = *(const float4*)(h + (size_t)p*INTER + c*4);
        }
        __syncthreads();

        #pragma unroll
        for (int r = 0; r < 8; ++r) {
            const int i = i0 + r;
            const float* wrow = w2 + ((size_t)e * HIDDEN + i) * INTER;
            float4 a[3];
            #pragma unroll
            for (int j = 0; j < 3; ++j)
                a[j] = *(const float4*)(wrow + lane*4 + 256*j);
            for (int tau = 0; tau < gnp; ++tau) {
                float acc = 0.f;
                #pragma unroll
                for (int j = 0; j < 3; ++j) {
                    const float4 hv = *(const float4*)(&s_h[tau][lane*4 + 256*j]);
                    acc += a[j].x*hv.x + a[j].y*hv.y + a[j].z*hv.z + a[j].w*hv.w;
                }
                #pragma unroll
                for (int m = 32; m > 0; m >>= 1)
                    acc += __shfl_xor(acc, m, 64);
                if (lane == 0) {
                    int p = s_plist[g*GRP + tau];
                    y[(size_t)p * HIDDEN + i] = acc;
                }
            }
        }
        __syncthreads();
    }
}

// ---------------------------------------------------------------------------
// Pass 3: out[t][i] = tw[t][0]*y[2t][i] + tw[t][1]*y[2t+1][i]
// ---------------------------------------------------------------------------
__global__ __launch_bounds__(256) void moe_combine(
    const float* __restrict__ tw,   // [64][2]
    const float* __restrict__ y,    // [128][1024]
    float*       __restrict__ out)  // [64][1024]
{
    int idx = blockIdx.x * 256 + threadIdx.x;       // 16384 float4 slots
    int t = idx / (HIDDEN/4);
    int c = idx % (HIDDEN/4);
    float w0 = tw[t*2+0], w1 = tw[t*2+1];
    float4 a = *(const float4*)(y + (size_t)(2*t  )*HIDDEN + c*4);
    float4 b = *(const float4*)(y + (size_t)(2*t+1)*HIDDEN + c*4);
    float4 o;
    o.x = w0*a.x + w1*b.x;
    o.y = w0*a.y + w1*b.y;
    o.z = w0*a.z + w1*b.z;
    o.w = w0*a.w + w1*b.w;
    *(float4*)(out + (size_t)t*HIDDEN + c*4) = o;
}

extern "C" void kernel_launch(void* const* d_in, const int* in_sizes, int n_in,
                              void* d_out, int out_size, void* d_ws, size_t ws_size,
                              hipStream_t stream) {
    const float* x   = (const float*)d_in[0];
    const int*   ids = (const int*)  d_in[1];
    const float* tw  = (const float*)d_in[2];
    const float* w13 = (const float*)d_in[3];
    const float* w2  = (const float*)d_in[4];
    float* out = (float*)d_out;

    float* h = (float*)d_ws;                 // 128*768  floats
    float* y = h + (size_t)NPAIRS * INTER;   // 128*1024 floats

    dim3 g1(INTER/32, NUM_EXPERTS);    // (24, 16)
    moe_pass1<<<g1, 256, 0, stream>>>(x, ids, w13, h);

    dim3 g2(HIDDEN/32, NUM_EXPERTS);   // (32, 16)
    moe_pass2<<<g2, 256, 0, stream>>>(ids, w2, h, y);

    moe_combine<<<(TOKENS*HIDDEN/4)/256, 256, 0, stream>>>(tw, y, out);
}

// Round 3
// 54.967 us; speedup vs baseline: 1.8642x; 1.8642x over previous
//
#include <hip/hip_runtime.h>
#include <math.h>

#define NUM_EXPERTS 16
#define HIDDEN 1024
#define INTER 768
#define TOKENS 64
#define TOPK 2
#define NPAIRS (TOKENS*TOPK)   // 128
#define GRP 8                  // tokens staged per group
#define NZ 2                   // token-group slices in grid.z

// Deterministic expert pair-list build: wave 0 ballots over pairs [0,64) and
// [64,128). List is sorted by pair index -> identical across all blocks.
__device__ inline void build_plist(const int* __restrict__ topk_ids, int e,
                                   int tid, int* s_plist, int* s_np) {
    if (tid < 64) {
        const int lane = tid;
        int m0 = (topk_ids[lane]      == e);
        int m1 = (topk_ids[lane + 64] == e);
        unsigned long long b0 = __ballot(m0);
        unsigned long long b1 = __ballot(m1);
        int n0 = __popcll(b0);
        unsigned long long below = (lane == 0) ? 0ull : ((1ull << lane) - 1ull);
        if (m0) s_plist[__popcll(b0 & below)]      = lane;
        if (m1) s_plist[n0 + __popcll(b1 & below)] = lane + 64;
        if (lane == 0) *s_np = n0 + __popcll(b1);
    }
    __syncthreads();
}

// ---------------------------------------------------------------------------
// Pass 1: h[p][o] = silu(x[t]·w1[e,o,:]) * (x[t]·w3[e,o,:])
// grid = (48 row-chunks of 16, 16 experts, NZ), block = 256
// ---------------------------------------------------------------------------
__global__ __launch_bounds__(256) void moe_pass1(
    const float* __restrict__ x,        // [64][1024]
    const int*   __restrict__ topk_ids, // [128]
    const float* __restrict__ w13,      // [16][1536][1024]
    float*       __restrict__ h)        // [128][768]
{
    const int e    = blockIdx.y;
    const int z    = blockIdx.z;
    const int wave = threadIdx.x >> 6;
    const int o0   = blockIdx.x * 16 + wave * 4;
    const int tid  = threadIdx.x;
    const int lane = tid & 63;

    __shared__ int   s_plist[NPAIRS];
    __shared__ int   s_np;
    __shared__ float s_x[GRP][HIDDEN];   // 32 KB

    build_plist(topk_ids, e, tid, s_plist, &s_np);
    const int np = s_np;

    for (int g = z; g * GRP < np; g += NZ) {
        const int gnp = min(GRP, np - g * GRP);
        for (int idx = tid; idx < gnp * (HIDDEN/4); idx += 256) {
            int tau = idx / (HIDDEN/4);
            int c   = idx % (HIDDEN/4);
            int t   = s_plist[g*GRP + tau] >> 1;
            *(float4*)(&s_x[tau][c*4]) = *(const float4*)(x + (size_t)t*HIDDEN + c*4);
        }
        __syncthreads();

        #pragma unroll
        for (int rr = 0; rr < 4; rr += 2) {
            const int oA = o0 + rr;
            const int oB = o0 + rr + 1;
            const float* w1A = w13 + ((size_t)e * (2*INTER) + oA) * HIDDEN;
            const float* w3A = w13 + ((size_t)e * (2*INTER) + INTER + oA) * HIDDEN;
            const float* w1B = w13 + ((size_t)e * (2*INTER) + oB) * HIDDEN;
            const float* w3B = w13 + ((size_t)e * (2*INTER) + INTER + oB) * HIDDEN;
            float4 a1A[4], a3A[4], a1B[4], a3B[4];
            #pragma unroll
            for (int j = 0; j < 4; ++j) {
                a1A[j] = *(const float4*)(w1A + lane*4 + 256*j);
                a3A[j] = *(const float4*)(w3A + lane*4 + 256*j);
                a1B[j] = *(const float4*)(w1B + lane*4 + 256*j);
                a3B[j] = *(const float4*)(w3B + lane*4 + 256*j);
            }
            for (int tau = 0; tau < gnp; ++tau) {
                float acc1A = 0.f, acc3A = 0.f, acc1B = 0.f, acc3B = 0.f;
                #pragma unroll
                for (int j = 0; j < 4; ++j) {
                    const float4 xv = *(const float4*)(&s_x[tau][lane*4 + 256*j]);
                    acc1A += a1A[j].x*xv.x + a1A[j].y*xv.y + a1A[j].z*xv.z + a1A[j].w*xv.w;
                    acc3A += a3A[j].x*xv.x + a3A[j].y*xv.y + a3A[j].z*xv.z + a3A[j].w*xv.w;
                    acc1B += a1B[j].x*xv.x + a1B[j].y*xv.y + a1B[j].z*xv.z + a1B[j].w*xv.w;
                    acc3B += a3B[j].x*xv.x + a3B[j].y*xv.y + a3B[j].z*xv.z + a3B[j].w*xv.w;
                }
                #pragma unroll
                for (int m = 32; m > 0; m >>= 1) {
                    acc1A += __shfl_xor(acc1A, m, 64);
                    acc3A += __shfl_xor(acc3A, m, 64);
                    acc1B += __shfl_xor(acc1B, m, 64);
                    acc3B += __shfl_xor(acc3B, m, 64);
                }
                if (lane == 0) {
                    int p = s_plist[g*GRP + tau];
                    float gA = acc1A / (1.f + expf(-acc1A));
                    float gB = acc1B / (1.f + expf(-acc1B));
                    h[(size_t)p * INTER + oA] = gA * acc3A;
                    h[(size_t)p * INTER + oB] = gB * acc3B;
                }
            }
        }
        __syncthreads();
    }
}

// ---------------------------------------------------------------------------
// Pass 2: y[p][i] = sum_o h[p][o] * w2[e][i][o]
// grid = (64 row-chunks of 16, 16 experts, NZ), block = 256
// ---------------------------------------------------------------------------
__global__ __launch_bounds__(256) void moe_pass2(
    const int*   __restrict__ topk_ids, // [128]
    const float* __restrict__ w2,       // [16][1024][768]
    const float* __restrict__ h,        // [128][768]
    float*       __restrict__ y)        // [128][1024]
{
    const int e    = blockIdx.y;
    const int z    = blockIdx.z;
    const int wave = threadIdx.x >> 6;
    const int i0   = blockIdx.x * 16 + wave * 4;
    const int tid  = threadIdx.x;
    const int lane = tid & 63;

    __shared__ int   s_plist[NPAIRS];
    __shared__ int   s_np;
    __shared__ float s_h[GRP][INTER];    // 24 KB

    build_plist(topk_ids, e, tid, s_plist, &s_np);
    const int np = s_np;

    for (int g = z; g * GRP < np; g += NZ) {
        const int gnp = min(GRP, np - g * GRP);
        for (int idx = tid; idx < gnp * (INTER/4); idx += 256) {
            int tau = idx / (INTER/4);
            int c   = idx % (INTER/4);
            int p   = s_plist[g*GRP + tau];
            *(float4*)(&s_h[tau][c*4]) = *(const float4*)(h + (size_t)p*INTER + c*4);
        }
        __syncthreads();

        #pragma unroll
        for (int rr = 0; rr < 4; rr += 2) {
            const int iA = i0 + rr;
            const int iB = i0 + rr + 1;
            const float* wA = w2 + ((size_t)e * HIDDEN + iA) * INTER;
            const float* wB = w2 + ((size_t)e * HIDDEN + iB) * INTER;
            float4 aA[3], aB[3];
            #pragma unroll
            for (int j = 0; j < 3; ++j) {
                aA[j] = *(const float4*)(wA + lane*4 + 256*j);
                aB[j] = *(const float4*)(wB + lane*4 + 256*j);
            }
            for (int tau = 0; tau < gnp; ++tau) {
                float accA = 0.f, accB = 0.f;
                #pragma unroll
                for (int j = 0; j < 3; ++j) {
                    const float4 hv = *(const float4*)(&s_h[tau][lane*4 + 256*j]);
                    accA += aA[j].x*hv.x + aA[j].y*hv.y + aA[j].z*hv.z + aA[j].w*hv.w;
                    accB += aB[j].x*hv.x + aB[j].y*hv.y + aB[j].z*hv.z + aB[j].w*hv.w;
                }
                #pragma unroll
                for (int m = 32; m > 0; m >>= 1) {
                    accA += __shfl_xor(accA, m, 64);
                    accB += __shfl_xor(accB, m, 64);
                }
                if (lane == 0) {
                    int p = s_plist[g*GRP + tau];
                    y[(size_t)p * HIDDEN + iA] = accA;
                    y[(size_t)p * HIDDEN + iB] = accB;
                }
            }
        }
        __syncthreads();
    }
}

// ---------------------------------------------------------------------------
// Pass 3: out[t][i] = tw[t][0]*y[2t][i] + tw[t][1]*y[2t+1][i]
// ---------------------------------------------------------------------------
__global__ __launch_bounds__(256) void moe_combine(
    const float* __restrict__ tw,   // [64][2]
    const float* __restrict__ y,    // [128][1024]
    float*       __restrict__ out)  // [64][1024]
{
    int idx = blockIdx.x * 256 + threadIdx.x;       // 16384 float4 slots
    int t = idx / (HIDDEN/4);
    int c = idx % (HIDDEN/4);
    float w0 = tw[t*2+0], w1 = tw[t*2+1];
    float4 a = *(const float4*)(y + (size_t)(2*t  )*HIDDEN + c*4);
    float4 b = *(const float4*)(y + (size_t)(2*t+1)*HIDDEN + c*4);
    float4 o;
    o.x = w0*a.x + w1*b.x;
    o.y = w0*a.y + w1*b.y;
    o.z = w0*a.z + w1*b.z;
    o.w = w0*a.w + w1*b.w;
    *(float4*)(out + (size_t)t*HIDDEN + c*4) = o;
}

extern "C" void kernel_launch(void* const* d_in, const int* in_sizes, int n_in,
                              void* d_out, int out_size, void* d_ws, size_t ws_size,
                              hipStream_t stream) {
    const float* x   = (const float*)d_in[0];
    const int*   ids = (const int*)  d_in[1];
    const float* tw  = (const float*)d_in[2];
    const float* w13 = (const float*)d_in[3];
    const float* w2  = (const float*)d_in[4];
    float* out = (float*)d_out;

    float* h = (float*)d_ws;                 // 128*768  floats
    float* y = h + (size_t)NPAIRS * INTER;   // 128*1024 floats

    dim3 g1(INTER/16, NUM_EXPERTS, NZ);    // (48, 16, 2)
    moe_pass1<<<g1, 256, 0, stream>>>(x, ids, w13, h);

    dim3 g2(HIDDEN/16, NUM_EXPERTS, NZ);   // (64, 16, 2)
    moe_pass2<<<g2, 256, 0, stream>>>(ids, w2, h, y);

    moe_combine<<<(TOKENS*HIDDEN/4)/256, 256, 0, stream>>>(tw, y, out);
}